// Round 1
// baseline (299.238 us; speedup 1.0000x reference)
//
#include <hip/hip_runtime.h>
#include <hip/hip_bf16.h>

typedef unsigned short u16;
typedef __attribute__((ext_vector_type(8))) short short8;
typedef __attribute__((ext_vector_type(4))) float f32x4;

__device__ __forceinline__ u16 f2b(float f) {
  __hip_bfloat16 h = __float2bfloat16(f);
  return __builtin_bit_cast(unsigned short, h);
}
__device__ __forceinline__ float b2f(u16 u) {
  __hip_bfloat16 h = __builtin_bit_cast(__hip_bfloat16, u);
  return __bfloat162float(h);
}

// ---------------- K1: LayerNorm(msa_act) -> x bf16 [32768][256] ----------------
__global__ __launch_bounds__(256) void k_ln_msa(
    const float* __restrict__ msa, const float* __restrict__ sc,
    const float* __restrict__ bi, u16* __restrict__ xb) {
  const int wid = threadIdx.x >> 6, lane = threadIdx.x & 63;
  const int row = blockIdx.x * 4 + wid;
  const float4 v = ((const float4*)(msa + (size_t)row * 256))[lane];
  float s = v.x + v.y + v.z + v.w;
  float s2 = v.x * v.x + v.y * v.y + v.z * v.z + v.w * v.w;
#pragma unroll
  for (int m = 1; m < 64; m <<= 1) { s += __shfl_xor(s, m); s2 += __shfl_xor(s2, m); }
  const float mu = s * (1.f / 256.f);
  const float r = rsqrtf(s2 * (1.f / 256.f) - mu * mu + 1e-5f);
  const int c0 = lane * 4;
  const float4 scv = ((const float4*)sc)[lane];
  const float4 biv = ((const float4*)bi)[lane];
  ushort4 o;
  o.x = f2b((v.x - mu) * r * scv.x + biv.x);
  o.y = f2b((v.y - mu) * r * scv.y + biv.y);
  o.z = f2b((v.z - mu) * r * scv.z + biv.z);
  o.w = f2b((v.w - mu) * r * scv.w + biv.w);
  *(ushort4*)(xb + (size_t)row * 256 + c0) = o;
}

// ------- K2: LayerNorm(pair_act) + feat2d einsum -> bias[h][q][k] fp32 --------
__global__ __launch_bounds__(256) void k_ln_pair(
    const float* __restrict__ pair, const float* __restrict__ sc,
    const float* __restrict__ bi, const float* __restrict__ fw,
    float* __restrict__ biasP) {
  const int wid = threadIdx.x >> 6, lane = threadIdx.x & 63;
  const int row = blockIdx.x * 4 + wid;  // row = q*256 + k
  const float2 v = ((const float2*)(pair + (size_t)row * 128))[lane];
  float s = v.x + v.y, s2 = v.x * v.x + v.y * v.y;
#pragma unroll
  for (int m = 1; m < 64; m <<= 1) { s += __shfl_xor(s, m); s2 += __shfl_xor(s2, m); }
  const float mu = s * (1.f / 128.f);
  const float r = rsqrtf(s2 * (1.f / 128.f) - mu * mu + 1e-5f);
  const int c0 = lane * 2;
  const float x0 = (v.x - mu) * r * sc[c0] + bi[c0];
  const float x1 = (v.y - mu) * r * sc[c0 + 1] + bi[c0 + 1];
  union { float4 v4[4]; float f[16]; } fu;
  const float4* f4 = (const float4*)(fw + c0 * 8);
  fu.v4[0] = f4[0]; fu.v4[1] = f4[1]; fu.v4[2] = f4[2]; fu.v4[3] = f4[3];
  float ph[8];
#pragma unroll
  for (int h = 0; h < 8; h++) ph[h] = x0 * fu.f[h] + x1 * fu.f[8 + h];
#pragma unroll
  for (int h = 0; h < 8; h++) {
#pragma unroll
    for (int m = 1; m < 64; m <<= 1) ph[h] += __shfl_xor(ph[h], m);
    if (lane == h) biasP[h * 65536 + row] = ph[h];
  }
}

// ------ K3: weights -> bf16, transposed to [N][K] for B-fragment reads -------
__global__ __launch_bounds__(256) void k_conv(
    const float* __restrict__ qw, const float* __restrict__ kw,
    const float* __restrict__ vw, const float* __restrict__ gw,
    const float* __restrict__ ow, u16* __restrict__ Wt, u16* __restrict__ OWt) {
  const int idx = blockIdx.x * 256 + threadIdx.x;
  if (idx < 262144) {
    const int a = idx & 255, nl = (idx >> 8) & 255, proj = idx >> 16;
    const float* w = proj == 0 ? qw : proj == 1 ? kw : proj == 2 ? vw : gw;
    float val = w[a * 256 + nl];
    if (proj == 0) val *= 0.17677669529663687f;  // 1/sqrt(32) folded into q_w
    Wt[idx] = f2b(val);
  } else {
    const int i2 = idx - 262144;
    const int o = i2 >> 8, j = i2 & 255;
    OWt[i2] = f2b(ow[j * 256 + o]);  // o_w[h][c][o] -> OWt[o][h*32+c]
  }
}

// -------- K4/K6: bf16 MFMA GEMM, A[M][256] @ Bt[N][256]^T, 128x128 tile -------
template <bool OUT_BF16>
__global__ __launch_bounds__(256) void k_gemm(
    const u16* __restrict__ A, const u16* __restrict__ Bt,
    void* __restrict__ out, const float* __restrict__ obias, const int N) {
  __shared__ u16 As[128 * 40];  // row stride 40 bf16 (80B): 2-way-only bank aliasing
  __shared__ u16 Bs[128 * 40];
  const int tid = threadIdx.x, wid = tid >> 6, lane = tid & 63;
  const int quad = lane >> 4, l16 = lane & 15;
  const int wm = (wid >> 1) * 64, wn = (wid & 1) * 64;
  const int bm = blockIdx.x, bn = blockIdx.y;
  const int srow = tid >> 1, shalf = tid & 1;
  const u16* ga = A + (size_t)(bm * 128 + srow) * 256 + shalf * 16;
  const u16* gb = Bt + (size_t)(bn * 128 + srow) * 256 + shalf * 16;
  u16* wa = As + srow * 40 + shalf * 16;
  u16* wb = Bs + srow * 40 + shalf * 16;
  f32x4 acc[4][4];
#pragma unroll
  for (int i = 0; i < 4; i++)
#pragma unroll
    for (int j = 0; j < 4; j++) acc[i][j] = f32x4{0.f, 0.f, 0.f, 0.f};
  for (int k0 = 0; k0 < 256; k0 += 32) {
    const uint4 a0 = *(const uint4*)(ga + k0);
    const uint4 a1 = *(const uint4*)(ga + k0 + 8);
    const uint4 b0 = *(const uint4*)(gb + k0);
    const uint4 b1 = *(const uint4*)(gb + k0 + 8);
    __syncthreads();  // previous iter's LDS reads done
    *(uint4*)wa = a0; *(uint4*)(wa + 8) = a1;
    *(uint4*)wb = b0; *(uint4*)(wb + 8) = b1;
    __syncthreads();
    short8 af[4], bf[4];
#pragma unroll
    for (int i = 0; i < 4; i++)
      af[i] = *(const short8*)(As + (wm + i * 16 + l16) * 40 + quad * 8);
#pragma unroll
    for (int j = 0; j < 4; j++)
      bf[j] = *(const short8*)(Bs + (wn + j * 16 + l16) * 40 + quad * 8);
#pragma unroll
    for (int i = 0; i < 4; i++)
#pragma unroll
      for (int j = 0; j < 4; j++)
        acc[i][j] = __builtin_amdgcn_mfma_f32_16x16x32_bf16(af[i], bf[j], acc[i][j], 0, 0, 0);
  }
#pragma unroll
  for (int i = 0; i < 4; i++)
#pragma unroll
    for (int j = 0; j < 4; j++)
#pragma unroll
      for (int r = 0; r < 4; r++) {
        const int gm = bm * 128 + wm + i * 16 + quad * 4 + r;  // C/D: row=quad*4+reg
        const int gn = bn * 128 + wn + j * 16 + l16;           //      col=lane&15
        const float v = acc[i][j][r];
        if (OUT_BF16) ((u16*)out)[(size_t)gm * N + gn] = f2b(v);
        else ((float*)out)[(size_t)gm * N + gn] = v + obias[gn];
      }
}

// ---- K5: attention per (b, h, q-half): S in regs, softmax, P->LDS->PV, gate ----
__global__ __launch_bounds__(256) void k_attn(
    const u16* __restrict__ Y, const float* __restrict__ biasP,
    const float* __restrict__ mask, const float* __restrict__ gb,
    u16* __restrict__ Z) {
  __shared__ u16 Vt[32 * 264];       // V^T: [c][k], stride 264 (2-way aliasing only)
  __shared__ u16 Ps[4][32 * 136];    // per-wave P chunk [32 q][128 k], stride 136
  const int b = blockIdx.x, h = blockIdx.y, qh = blockIdx.z;
  const int tid = threadIdx.x, wid = tid >> 6, lane = tid & 63;
  const int quad = lane >> 4, l16 = lane & 15;
  const int q0 = qh * 128 + wid * 32;
  const u16* Yb = Y + (size_t)b * 256 * 1024;
  {  // stage V transposed
    const int k = tid;
    const u16* src = Yb + (size_t)k * 1024 + 512 + h * 32;
    union { uint4 v4[4]; u16 u[32]; } uu;
    uu.v4[0] = *(const uint4*)(src);
    uu.v4[1] = *(const uint4*)(src + 8);
    uu.v4[2] = *(const uint4*)(src + 16);
    uu.v4[3] = *(const uint4*)(src + 24);
#pragma unroll
    for (int c = 0; c < 32; c++) Vt[c * 264 + k] = uu.u[c];
  }
  __syncthreads();
  // ---- S = Q K^T : wave computes 32 q x 256 k in 32 MFMAs ----
  f32x4 S[2][16];
#pragma unroll
  for (int mi = 0; mi < 2; mi++)
#pragma unroll
    for (int ni = 0; ni < 16; ni++) S[mi][ni] = f32x4{0.f, 0.f, 0.f, 0.f};
  short8 aq[2];
#pragma unroll
  for (int mi = 0; mi < 2; mi++)
    aq[mi] = *(const short8*)(Yb + (size_t)(q0 + mi * 16 + l16) * 1024 + h * 32 + quad * 8);
#pragma unroll
  for (int ni = 0; ni < 16; ni++) {
    const short8 bk = *(const short8*)(Yb + (size_t)(ni * 16 + l16) * 1024 + 256 + h * 32 + quad * 8);
    S[0][ni] = __builtin_amdgcn_mfma_f32_16x16x32_bf16(aq[0], bk, S[0][ni], 0, 0, 0);
    S[1][ni] = __builtin_amdgcn_mfma_f32_16x16x32_bf16(aq[1], bk, S[1][ni], 0, 0, 0);
  }
  // ---- + pair bias + mask bias, softmax over k (row = quad*4+r) ----
  float maskv[16];
#pragma unroll
  for (int ni = 0; ni < 16; ni++)
    maskv[ni] = 1e9f * (mask[b * 256 + ni * 16 + l16] - 1.f);
  float li[2][4];
#pragma unroll
  for (int mi = 0; mi < 2; mi++) {
#pragma unroll
    for (int r = 0; r < 4; r++) {
      const int qg = q0 + mi * 16 + quad * 4 + r;
      const float* bp = biasP + (h << 16) + qg * 256 + l16;
      float mx = -1e30f;
#pragma unroll
      for (int ni = 0; ni < 16; ni++) {
        const float sv = S[mi][ni][r] + bp[ni * 16] + maskv[ni];
        S[mi][ni][r] = sv;
        mx = fmaxf(mx, sv);
      }
#pragma unroll
      for (int d = 1; d < 16; d <<= 1) mx = fmaxf(mx, __shfl_xor(mx, d));
      float l = 0.f;
#pragma unroll
      for (int ni = 0; ni < 16; ni++) {
        const float p = __expf(S[mi][ni][r] - mx);
        S[mi][ni][r] = p;
        l += p;
      }
#pragma unroll
      for (int d = 1; d < 16; d <<= 1) l += __shfl_xor(l, d);
      li[mi][r] = 1.f / l;
    }
  }
  // ---- P @ V over two k-halves through per-wave LDS (C/D -> A layout) ----
  f32x4 O[2][2];
#pragma unroll
  for (int mi = 0; mi < 2; mi++)
#pragma unroll
    for (int nj = 0; nj < 2; nj++) O[mi][nj] = f32x4{0.f, 0.f, 0.f, 0.f};
  u16* Pw = Ps[wid];
  for (int half = 0; half < 2; half++) {
    __syncthreads();
#pragma unroll
    for (int mi = 0; mi < 2; mi++)
#pragma unroll
      for (int nih = 0; nih < 8; nih++) {
        const int ni = half * 8 + nih;
#pragma unroll
        for (int r = 0; r < 4; r++)
          Pw[(mi * 16 + quad * 4 + r) * 136 + nih * 16 + l16] = f2b(S[mi][ni][r]);
      }
    __syncthreads();
#pragma unroll
    for (int kb = 0; kb < 4; kb++) {
      short8 ap0 = *(const short8*)(Pw + (l16) * 136 + kb * 32 + quad * 8);
      short8 ap1 = *(const short8*)(Pw + (16 + l16) * 136 + kb * 32 + quad * 8);
#pragma unroll
      for (int nj = 0; nj < 2; nj++) {
        const short8 bv = *(const short8*)(Vt + (nj * 16 + l16) * 264 + half * 128 + kb * 32 + quad * 8);
        O[0][nj] = __builtin_amdgcn_mfma_f32_16x16x32_bf16(ap0, bv, O[0][nj], 0, 0, 0);
        O[1][nj] = __builtin_amdgcn_mfma_f32_16x16x32_bf16(ap1, bv, O[1][nj], 0, 0, 0);
      }
    }
  }
  // ---- epilogue: normalize by l, gate sigmoid, write Z bf16 ----
  const float* gbh = gb + h * 32;
#pragma unroll
  for (int mi = 0; mi < 2; mi++)
#pragma unroll
    for (int nj = 0; nj < 2; nj++)
#pragma unroll
      for (int r = 0; r < 4; r++) {
        const int qg = q0 + mi * 16 + quad * 4 + r;
        const int c = nj * 16 + l16;
        const float wa = O[mi][nj][r] * li[mi][r];
        const float gv = b2f(Yb[(size_t)qg * 1024 + 768 + h * 32 + c]) + gbh[c];
        const float gate = 1.f / (1.f + __expf(-gv));
        Z[((size_t)b * 256 + qg) * 256 + h * 32 + c] = f2b(wa * gate);
      }
}

extern "C" void kernel_launch(void* const* d_in, const int* in_sizes, int n_in,
                              void* d_out, int out_size, void* d_ws, size_t ws_size,
                              hipStream_t stream) {
  const float* msa  = (const float*)d_in[0];
  const float* mask = (const float*)d_in[1];
  const float* pair = (const float*)d_in[2];
  const float* qns  = (const float*)d_in[3];
  const float* qnb  = (const float*)d_in[4];
  const float* pns  = (const float*)d_in[5];
  const float* pnb  = (const float*)d_in[6];
  const float* f2w  = (const float*)d_in[7];
  const float* qw   = (const float*)d_in[8];
  const float* kw   = (const float*)d_in[9];
  const float* vw   = (const float*)d_in[10];
  const float* gw   = (const float*)d_in[11];
  const float* gbp  = (const float*)d_in[12];
  const float* ow   = (const float*)d_in[13];
  const float* ob   = (const float*)d_in[14];
  float* out = (float*)d_out;
  char* ws = (char*)d_ws;
  // workspace layout (103.4 MB total)
  u16*   xb    = (u16*)(ws);                  // 16777216 B
  u16*   Wt    = (u16*)(ws + 16777216);       //   524288 B
  u16*   OWt   = (u16*)(ws + 17301504);       //   131072 B
  float* biasP = (float*)(ws + 17432576);     //  2097152 B
  u16*   Y     = (u16*)(ws + 19529728);       // 67108864 B
  u16*   Z     = (u16*)(ws + 86638592);       // 16777216 B

  k_ln_msa<<<8192, 256, 0, stream>>>(msa, qns, qnb, xb);
  k_ln_pair<<<16384, 256, 0, stream>>>(pair, pns, pnb, f2w, biasP);
  k_conv<<<1280, 256, 0, stream>>>(qw, kw, vw, gw, ow, Wt, OWt);
  k_gemm<true><<<dim3(256, 8), 256, 0, stream>>>(xb, Wt, (void*)Y, nullptr, 1024);
  k_attn<<<dim3(128, 8, 2), 256, 0, stream>>>(Y, biasP, mask, gbp, Z);
  k_gemm<false><<<dim3(256, 2), 256, 0, stream>>>(Z, OWt, (void*)out, ob, 256);
}

// Round 2
// 287.249 us; speedup vs baseline: 1.0417x; 1.0417x over previous
//
#include <hip/hip_runtime.h>
#include <hip/hip_bf16.h>

typedef unsigned short u16;
typedef unsigned int u32;
typedef __attribute__((ext_vector_type(8))) short short8;
typedef __attribute__((ext_vector_type(4))) float f32x4;

// cheap RNE f32->bf16 (no NaN handling; values here are finite)
__device__ __forceinline__ u16 f2b(float f) {
  u32 u = __builtin_bit_cast(u32, f);
  u += 0x7fffu + ((u >> 16) & 1u);
  return (u16)(u >> 16);
}
// pack two f32 -> two bf16 in one u32 (lo = a, hi = b), RNE
__device__ __forceinline__ u32 pkb(float a, float b) {
  u32 ua = __builtin_bit_cast(u32, a);
  u32 ub = __builtin_bit_cast(u32, b);
  ua += 0x7fffu + ((ua >> 16) & 1u);
  ub += 0x7fffu + ((ub >> 16) & 1u);
  return (ua >> 16) | (ub & 0xffff0000u);
}
__device__ __forceinline__ float b2f(u16 u) {
  u32 x = ((u32)u) << 16;
  return __builtin_bit_cast(float, x);
}
// async global->LDS, 16B per lane; lds ptr must be wave-uniform
__device__ __forceinline__ void load_lds16(const u16* g, u16* l) {
  __builtin_amdgcn_global_load_lds(
      (const __attribute__((address_space(1))) void*)(uintptr_t)g,
      (__attribute__((address_space(3))) void*)(u32)(uintptr_t)l, 16, 0, 0);
}

// ---------------- K1: LayerNorm(msa_act) -> x bf16 [32768][256] ----------------
__global__ __launch_bounds__(256) void k_ln_msa(
    const float* __restrict__ msa, const float* __restrict__ sc,
    const float* __restrict__ bi, u16* __restrict__ xb) {
  const int wid = threadIdx.x >> 6, lane = threadIdx.x & 63;
  const int row = blockIdx.x * 4 + wid;
  const float4 v = ((const float4*)(msa + (size_t)row * 256))[lane];
  float s = v.x + v.y + v.z + v.w;
  float s2 = v.x * v.x + v.y * v.y + v.z * v.z + v.w * v.w;
#pragma unroll
  for (int m = 1; m < 64; m <<= 1) { s += __shfl_xor(s, m); s2 += __shfl_xor(s2, m); }
  const float mu = s * (1.f / 256.f);
  const float r = rsqrtf(s2 * (1.f / 256.f) - mu * mu + 1e-5f);
  const int c0 = lane * 4;
  const float4 scv = ((const float4*)sc)[lane];
  const float4 biv = ((const float4*)bi)[lane];
  uint2 o;
  o.x = pkb((v.x - mu) * r * scv.x + biv.x, (v.y - mu) * r * scv.y + biv.y);
  o.y = pkb((v.z - mu) * r * scv.z + biv.z, (v.w - mu) * r * scv.w + biv.w);
  *(uint2*)(xb + (size_t)row * 256 + c0) = o;
}

// -- K2: LayerNorm(pair_act) + feat2d einsum -> biasB[h][q][slot] fp32,
//    slot = (k&15)*16 + (k>>4)  (so attn lane l16 reads 16 contiguous floats) --
__global__ __launch_bounds__(256) void k_ln_pair(
    const float* __restrict__ pair, const float* __restrict__ sc,
    const float* __restrict__ bi, const float* __restrict__ fw,
    float* __restrict__ biasB) {
  const int wid = threadIdx.x >> 6, lane = threadIdx.x & 63;
  const int row = blockIdx.x * 4 + wid;  // row = q*256 + k
  const float2 v = ((const float2*)(pair + (size_t)row * 128))[lane];
  float s = v.x + v.y, s2 = v.x * v.x + v.y * v.y;
#pragma unroll
  for (int m = 1; m < 64; m <<= 1) { s += __shfl_xor(s, m); s2 += __shfl_xor(s2, m); }
  const float mu = s * (1.f / 128.f);
  const float r = rsqrtf(s2 * (1.f / 128.f) - mu * mu + 1e-5f);
  const int c0 = lane * 2;
  const float x0 = (v.x - mu) * r * sc[c0] + bi[c0];
  const float x1 = (v.y - mu) * r * sc[c0 + 1] + bi[c0 + 1];
  union { float4 v4[4]; float f[16]; } fu;
  const float4* f4 = (const float4*)(fw + c0 * 8);
  fu.v4[0] = f4[0]; fu.v4[1] = f4[1]; fu.v4[2] = f4[2]; fu.v4[3] = f4[3];
  float ph[8];
#pragma unroll
  for (int h = 0; h < 8; h++) ph[h] = x0 * fu.f[h] + x1 * fu.f[8 + h];
#pragma unroll
  for (int h = 0; h < 8; h++) {
#pragma unroll
    for (int m = 1; m < 64; m <<= 1) ph[h] += __shfl_xor(ph[h], m);
  }
  const int q = row >> 8, kk = row & 255;
  const int slot = (kk & 15) * 16 + (kk >> 4);
  if (lane < 8) biasB[lane * 65536 + q * 256 + slot] = ph[lane];
}

// ------ K3: weights -> bf16, transposed to [N][K] for B-fragment reads -------
__global__ __launch_bounds__(256) void k_conv(
    const float* __restrict__ qw, const float* __restrict__ kw,
    const float* __restrict__ vw, const float* __restrict__ gw,
    const float* __restrict__ ow, u16* __restrict__ Wt, u16* __restrict__ OWt) {
  const int idx = blockIdx.x * 256 + threadIdx.x;
  if (idx < 262144) {
    const int a = idx & 255, nl = (idx >> 8) & 255, proj = idx >> 16;
    const float* w = proj == 0 ? qw : proj == 1 ? kw : proj == 2 ? vw : gw;
    float val = w[a * 256 + nl];
    if (proj == 0) val *= 0.17677669529663687f;  // 1/sqrt(32) folded into q_w
    Wt[idx] = f2b(val);
  } else {
    const int i2 = idx - 262144;
    const int o = i2 >> 8, j = i2 & 255;
    OWt[i2] = f2b(ow[j * 256 + o]);  // o_w[h][c][o] -> OWt[o][h*32+c]
  }
}

// ------ K4/K6: bf16 MFMA GEMM, A[M][256] @ Bt[N][256]^T, 128x128 tile,
//        m97-style global_load_lds(16B) staging into unpadded [128][32] ------
template <bool OUT_BF16>
__global__ __launch_bounds__(256) void k_gemm(
    const u16* __restrict__ A, const u16* __restrict__ Bt,
    void* __restrict__ out, const float* __restrict__ obias, const int N) {
  __shared__ u16 As[128 * 32];
  __shared__ u16 Bs[128 * 32];
  const int tid = threadIdx.x, wid = tid >> 6, lane = tid & 63;
  const int quad = lane >> 4, l16 = lane & 15;
  const int wm = (wid >> 1) * 64, wn = (wid & 1) * 64;
  const int bm = blockIdx.x, bn = blockIdx.y;
  // staging map: instr p in {0,1}: row = (p*4+wid)*16 + lane/4, col = (lane&3)*8
  const int r0 = wid * 16 + (lane >> 2);
  const int kc = (lane & 3) * 8;
  const u16* gA0 = A + (size_t)(bm * 128 + r0) * 256 + kc;
  const u16* gA1 = A + (size_t)(bm * 128 + 64 + r0) * 256 + kc;
  const u16* gB0 = Bt + (size_t)(bn * 128 + r0) * 256 + kc;
  const u16* gB1 = Bt + (size_t)(bn * 128 + 64 + r0) * 256 + kc;
  u16* lA0 = As + wid * 512;          // (wid)*1024 B
  u16* lA1 = As + 2048 + wid * 512;   // (4+wid)*1024 B
  u16* lB0 = Bs + wid * 512;
  u16* lB1 = Bs + 2048 + wid * 512;
  f32x4 acc[4][4];
#pragma unroll
  for (int i = 0; i < 4; i++)
#pragma unroll
    for (int j = 0; j < 4; j++) acc[i][j] = f32x4{0.f, 0.f, 0.f, 0.f};
  for (int k0 = 0; k0 < 256; k0 += 32) {
    __syncthreads();
    load_lds16(gA0 + k0, lA0);
    load_lds16(gA1 + k0, lA1);
    load_lds16(gB0 + k0, lB0);
    load_lds16(gB1 + k0, lB1);
    __syncthreads();
    short8 af[4], bf[4];
#pragma unroll
    for (int i = 0; i < 4; i++)
      af[i] = *(const short8*)(As + (wm + i * 16 + l16) * 32 + quad * 8);
#pragma unroll
    for (int j = 0; j < 4; j++)
      bf[j] = *(const short8*)(Bs + (wn + j * 16 + l16) * 32 + quad * 8);
#pragma unroll
    for (int i = 0; i < 4; i++)
#pragma unroll
      for (int j = 0; j < 4; j++)
        acc[i][j] = __builtin_amdgcn_mfma_f32_16x16x32_bf16(af[i], bf[j], acc[i][j], 0, 0, 0);
  }
#pragma unroll
  for (int i = 0; i < 4; i++)
#pragma unroll
    for (int j = 0; j < 4; j++)
#pragma unroll
      for (int r = 0; r < 4; r++) {
        const int gm = bm * 128 + wm + i * 16 + quad * 4 + r;  // C/D: row=quad*4+reg
        const int gn = bn * 128 + wn + j * 16 + l16;           //      col=lane&15
        const float v = acc[i][j][r];
        if (OUT_BF16) ((u16*)out)[(size_t)gm * N + gn] = f2b(v);
        else ((float*)out)[(size_t)gm * N + gn] = v + obias[gn];
      }
}

// ---- K5: attention per (b, h, q-quarter): 4 waves x 16 q; S in regs;
//      P/V use per-128-half k-permutation s=(k&15)*8+(k>>4) so P repack is
//      4x ds_write_b128 per half; per-wave Ps needs no barriers ----
__global__ __launch_bounds__(256, 4) void k_attn(
    const u16* __restrict__ Y, const float* __restrict__ biasB,
    const float* __restrict__ mask, const float* __restrict__ gb,
    u16* __restrict__ Z) {
  __shared__ u16 Vt[32 * 264];        // V^T permuted: [c][slot], 16.5 KB
  __shared__ u16 Ps[4][16 * 136];     // per-wave P chunk [16 q][128 slots], 17 KB
  const int b = blockIdx.x, h = blockIdx.y, qc = blockIdx.z;
  const int tid = threadIdx.x, wid = tid >> 6, lane = tid & 63;
  const int quad = lane >> 4, l16 = lane & 15;
  const int q0 = qc * 64 + wid * 16;
  const u16* Yb = Y + (size_t)b * 256 * 1024;
  // ---- stage V^T with permutation: thread t handles global slot t ----
  {
    const int s = tid & 127, h2 = tid >> 7;
    const int k = h2 * 128 + (s & 7) * 16 + (s >> 3);
    const u16* src = Yb + (size_t)k * 1024 + 512 + h * 32;
    union { uint4 v4[4]; u16 u[32]; } uu;
    uu.v4[0] = *(const uint4*)(src);
    uu.v4[1] = *(const uint4*)(src + 8);
    uu.v4[2] = *(const uint4*)(src + 16);
    uu.v4[3] = *(const uint4*)(src + 24);
#pragma unroll
    for (int c = 0; c < 32; c++) Vt[c * 264 + tid] = uu.u[c];
  }
  // ---- S = Q K^T : wave computes 16 q x 256 k in 16 MFMAs ----
  f32x4 S[16];
#pragma unroll
  for (int ni = 0; ni < 16; ni++) S[ni] = f32x4{0.f, 0.f, 0.f, 0.f};
  const short8 aq = *(const short8*)(Yb + (size_t)(q0 + l16) * 1024 + h * 32 + quad * 8);
#pragma unroll
  for (int ni = 0; ni < 16; ni++) {
    const short8 bk = *(const short8*)(Yb + (size_t)(ni * 16 + l16) * 1024 + 256 + h * 32 + quad * 8);
    S[ni] = __builtin_amdgcn_mfma_f32_16x16x32_bf16(aq, bk, S[ni], 0, 0, 0);
  }
  // ---- + pair bias (vectorized, pre-permuted) + mask, softmax over k ----
  float maskv[16];
#pragma unroll
  for (int ni = 0; ni < 16; ni++)
    maskv[ni] = 1e9f * (mask[b * 256 + ni * 16 + l16] - 1.f);
  float li[4];
#pragma unroll
  for (int r = 0; r < 4; r++) {
    const int qg = q0 + quad * 4 + r;
    const float4* bp = (const float4*)(biasB + ((h * 256 + qg) << 8) + l16 * 16);
    const float4 b0 = bp[0], b1 = bp[1], b2 = bp[2], b3 = bp[3];
    float sv[16];
    sv[0] = S[0][r] + b0.x + maskv[0];   sv[1] = S[1][r] + b0.y + maskv[1];
    sv[2] = S[2][r] + b0.z + maskv[2];   sv[3] = S[3][r] + b0.w + maskv[3];
    sv[4] = S[4][r] + b1.x + maskv[4];   sv[5] = S[5][r] + b1.y + maskv[5];
    sv[6] = S[6][r] + b1.z + maskv[6];   sv[7] = S[7][r] + b1.w + maskv[7];
    sv[8] = S[8][r] + b2.x + maskv[8];   sv[9] = S[9][r] + b2.y + maskv[9];
    sv[10] = S[10][r] + b2.z + maskv[10]; sv[11] = S[11][r] + b2.w + maskv[11];
    sv[12] = S[12][r] + b3.x + maskv[12]; sv[13] = S[13][r] + b3.y + maskv[13];
    sv[14] = S[14][r] + b3.z + maskv[14]; sv[15] = S[15][r] + b3.w + maskv[15];
    float mx = -1e30f;
#pragma unroll
    for (int ni = 0; ni < 16; ni++) mx = fmaxf(mx, sv[ni]);
#pragma unroll
    for (int d = 1; d < 16; d <<= 1) mx = fmaxf(mx, __shfl_xor(mx, d));
    float l = 0.f;
#pragma unroll
    for (int ni = 0; ni < 16; ni++) {
      const float p = __expf(sv[ni] - mx);
      S[ni][r] = p;
      l += p;
    }
#pragma unroll
    for (int d = 1; d < 16; d <<= 1) l += __shfl_xor(l, d);
    li[r] = 1.f / l;
  }
  __syncthreads();  // V staging visible to all waves (hidden behind S+softmax)
  // ---- P @ V in two k-halves through per-wave LDS (no barriers needed) ----
  f32x4 O[2];
  O[0] = f32x4{0.f, 0.f, 0.f, 0.f};
  O[1] = f32x4{0.f, 0.f, 0.f, 0.f};
  u16* Pw = Ps[wid];
#pragma unroll
  for (int h2 = 0; h2 < 2; h2++) {
#pragma unroll
    for (int r = 0; r < 4; r++) {
      uint4 w;  // slots l16*8 .. l16*8+7 hold k = h2*128 + nih*16 + l16
      w.x = pkb(S[h2 * 8 + 0][r], S[h2 * 8 + 1][r]);
      w.y = pkb(S[h2 * 8 + 2][r], S[h2 * 8 + 3][r]);
      w.z = pkb(S[h2 * 8 + 4][r], S[h2 * 8 + 5][r]);
      w.w = pkb(S[h2 * 8 + 6][r], S[h2 * 8 + 7][r]);
      *(uint4*)(Pw + (quad * 4 + r) * 136 + l16 * 8) = w;
    }
#pragma unroll
    for (int kb = 0; kb < 4; kb++) {
      const short8 ap = *(const short8*)(Pw + l16 * 136 + kb * 32 + quad * 8);
#pragma unroll
      for (int nj = 0; nj < 2; nj++) {
        const short8 bv = *(const short8*)(Vt + (nj * 16 + l16) * 264 + h2 * 128 + kb * 32 + quad * 8);
        O[nj] = __builtin_amdgcn_mfma_f32_16x16x32_bf16(ap, bv, O[nj], 0, 0, 0);
      }
    }
  }
  // ---- epilogue: normalize by l, gate sigmoid, write Z bf16 ----
  const float* gbh = gb + h * 32;
#pragma unroll
  for (int nj = 0; nj < 2; nj++)
#pragma unroll
    for (int r = 0; r < 4; r++) {
      const int qg = q0 + quad * 4 + r;
      const int c = nj * 16 + l16;
      const float wa = O[nj][r] * li[r];
      const float gv = b2f(Yb[(size_t)qg * 1024 + 768 + h * 32 + c]) + gbh[c];
      const float gate = 1.f / (1.f + __expf(-gv));
      Z[((size_t)b * 256 + qg) * 256 + h * 32 + c] = f2b(wa * gate);
    }
}

extern "C" void kernel_launch(void* const* d_in, const int* in_sizes, int n_in,
                              void* d_out, int out_size, void* d_ws, size_t ws_size,
                              hipStream_t stream) {
  const float* msa  = (const float*)d_in[0];
  const float* mask = (const float*)d_in[1];
  const float* pair = (const float*)d_in[2];
  const float* qns  = (const float*)d_in[3];
  const float* qnb  = (const float*)d_in[4];
  const float* pns  = (const float*)d_in[5];
  const float* pnb  = (const float*)d_in[6];
  const float* f2w  = (const float*)d_in[7];
  const float* qw   = (const float*)d_in[8];
  const float* kw   = (const float*)d_in[9];
  const float* vw   = (const float*)d_in[10];
  const float* gw   = (const float*)d_in[11];
  const float* gbp  = (const float*)d_in[12];
  const float* ow   = (const float*)d_in[13];
  const float* ob   = (const float*)d_in[14];
  float* out = (float*)d_out;
  char* ws = (char*)d_ws;
  u16*   xb    = (u16*)(ws);                  // 16777216 B
  u16*   Wt    = (u16*)(ws + 16777216);       //   524288 B
  u16*   OWt   = (u16*)(ws + 17301504);       //   131072 B
  float* biasB = (float*)(ws + 17432576);     //  2097152 B
  u16*   Y     = (u16*)(ws + 19529728);       // 67108864 B
  u16*   Z     = (u16*)(ws + 86638592);       // 16777216 B

  k_ln_msa<<<8192, 256, 0, stream>>>(msa, qns, qnb, xb);
  k_ln_pair<<<16384, 256, 0, stream>>>(pair, pns, pnb, f2w, biasB);
  k_conv<<<1280, 256, 0, stream>>>(qw, kw, vw, gw, ow, Wt, OWt);
  k_gemm<true><<<dim3(256, 8), 256, 0, stream>>>(xb, Wt, (void*)Y, nullptr, 1024);
  k_attn<<<dim3(128, 8, 4), 256, 0, stream>>>(Y, biasB, mask, gbp, Z);
  k_gemm<false><<<dim3(256, 2), 256, 0, stream>>>(Z, OWt, (void*)out, ob, 256);
}

// Round 3
// 245.184 us; speedup vs baseline: 1.2205x; 1.1716x over previous
//
#include <hip/hip_runtime.h>
#include <hip/hip_bf16.h>

typedef unsigned short u16;
typedef unsigned int u32;
typedef __attribute__((ext_vector_type(8))) short short8;
typedef __attribute__((ext_vector_type(4))) float f32x4;

// cheap RNE f32->bf16 (finite values only)
__device__ __forceinline__ u16 f2b(float f) {
  u32 u = __builtin_bit_cast(u32, f);
  u += 0x7fffu + ((u >> 16) & 1u);
  return (u16)(u >> 16);
}
__device__ __forceinline__ u32 pkb(float a, float b) {
  u32 ua = __builtin_bit_cast(u32, a);
  u32 ub = __builtin_bit_cast(u32, b);
  ua += 0x7fffu + ((ua >> 16) & 1u);
  ub += 0x7fffu + ((ub >> 16) & 1u);
  return (ua >> 16) | (ub & 0xffff0000u);
}
__device__ __forceinline__ float b2f(u16 u) {
  u32 x = ((u32)u) << 16;
  return __builtin_bit_cast(float, x);
}
__device__ __forceinline__ void load_lds16(const u16* g, u16* l) {
  __builtin_amdgcn_global_load_lds(
      (const __attribute__((address_space(1))) void*)(uintptr_t)g,
      (__attribute__((address_space(3))) void*)(u32)(uintptr_t)l, 16, 0, 0);
}

// k-slot permutation (64-granular): slot(k) = (k>>6)*64 + (k&15)*4 + ((k>>4)&3)
// inverse: k(slot) = (slot>>6)*64 + (slot&3)*16 + ((slot>>2)&15)

// ---------------- K1: LayerNorm(msa_act) -> x bf16 [32768][256] ----------------
__global__ __launch_bounds__(256) void k_ln_msa(
    const float* __restrict__ msa, const float* __restrict__ sc,
    const float* __restrict__ bi, u16* __restrict__ xb) {
  const int wid = threadIdx.x >> 6, lane = threadIdx.x & 63;
  const int row = blockIdx.x * 4 + wid;
  const float4 v = ((const float4*)(msa + (size_t)row * 256))[lane];
  float s = v.x + v.y + v.z + v.w;
  float s2 = v.x * v.x + v.y * v.y + v.z * v.z + v.w * v.w;
#pragma unroll
  for (int m = 1; m < 64; m <<= 1) { s += __shfl_xor(s, m); s2 += __shfl_xor(s2, m); }
  const float mu = s * (1.f / 256.f);
  const float r = rsqrtf(s2 * (1.f / 256.f) - mu * mu + 1e-5f);
  const int c0 = lane * 4;
  const float4 scv = ((const float4*)sc)[lane];
  const float4 biv = ((const float4*)bi)[lane];
  uint2 o;
  o.x = pkb((v.x - mu) * r * scv.x + biv.x, (v.y - mu) * r * scv.y + biv.y);
  o.y = pkb((v.z - mu) * r * scv.z + biv.z, (v.w - mu) * r * scv.w + biv.w);
  *(uint2*)(xb + (size_t)row * 256 + c0) = o;
}

// -- K2: LayerNorm(pair_act) + feat2d einsum -> biasB[h][q][slot(k)] fp32.
//    8 rows per wave (8-lane groups): coalesced reads, short reductions. --
__global__ __launch_bounds__(256) void k_ln_pair(
    const float* __restrict__ pair, const float* __restrict__ sc,
    const float* __restrict__ bi, const float* __restrict__ fw,
    float* __restrict__ biasB) {
  const int wid = threadIdx.x >> 6, lane = threadIdx.x & 63;
  const int R = blockIdx.x * 32 + wid * 8 + (lane >> 3);  // R = q*256 + k
  const int c0 = (lane & 7) * 16;
  const float4* src = (const float4*)(pair + (size_t)R * 128 + c0);
  const float4 a0 = src[0], a1 = src[1], a2 = src[2], a3 = src[3];
  float xs[16] = {a0.x, a0.y, a0.z, a0.w, a1.x, a1.y, a1.z, a1.w,
                  a2.x, a2.y, a2.z, a2.w, a3.x, a3.y, a3.z, a3.w};
  float s = 0.f, s2 = 0.f;
#pragma unroll
  for (int c = 0; c < 16; c++) { s += xs[c]; s2 += xs[c] * xs[c]; }
#pragma unroll
  for (int m = 1; m < 8; m <<= 1) { s += __shfl_xor(s, m); s2 += __shfl_xor(s2, m); }
  const float mu = s * (1.f / 128.f);
  const float r = rsqrtf(s2 * (1.f / 128.f) - mu * mu + 1e-5f);
  float ph[8] = {0.f, 0.f, 0.f, 0.f, 0.f, 0.f, 0.f, 0.f};
#pragma unroll
  for (int c = 0; c < 16; c++) {
    const float xn = (xs[c] - mu) * r * sc[c0 + c] + bi[c0 + c];
    const float4 w0 = *(const float4*)(fw + (c0 + c) * 8);
    const float4 w1 = *(const float4*)(fw + (c0 + c) * 8 + 4);
    ph[0] += xn * w0.x; ph[1] += xn * w0.y; ph[2] += xn * w0.z; ph[3] += xn * w0.w;
    ph[4] += xn * w1.x; ph[5] += xn * w1.y; ph[6] += xn * w1.z; ph[7] += xn * w1.w;
  }
#pragma unroll
  for (int m = 1; m < 8; m <<= 1) {
#pragma unroll
    for (int h = 0; h < 8; h++) ph[h] += __shfl_xor(ph[h], m);
  }
  const int h = lane & 7;
  const int q = R >> 8, k = R & 255;
  const int slot = ((k >> 6) << 6) + ((k & 15) << 2) + ((k >> 4) & 3);
  biasB[h * 65536 + q * 256 + slot] = ph[h];
}

// ------ K3: weights -> bf16, transposed to [N][K] for B-fragment reads -------
__global__ __launch_bounds__(256) void k_conv(
    const float* __restrict__ qw, const float* __restrict__ kw,
    const float* __restrict__ vw, const float* __restrict__ gw,
    const float* __restrict__ ow, u16* __restrict__ Wt, u16* __restrict__ OWt) {
  const int idx = blockIdx.x * 256 + threadIdx.x;
  if (idx < 262144) {
    const int a = idx & 255, nl = (idx >> 8) & 255, proj = idx >> 16;
    const float* w = proj == 0 ? qw : proj == 1 ? kw : proj == 2 ? vw : gw;
    float val = w[a * 256 + nl];
    if (proj == 0) val *= 0.17677669529663687f;  // 1/sqrt(32) folded into q_w
    Wt[idx] = f2b(val);
  } else {
    const int i2 = idx - 262144;
    const int o = i2 >> 8, j = i2 & 255;
    OWt[i2] = f2b(ow[j * 256 + o]);  // o_w[h][c][o] -> OWt[o][h*32+c]
  }
}

// ------ K4/K6: bf16 MFMA GEMM, A[M][256] @ Bt[N][256]^T, 128x128 tile,
//        global_load_lds(16B) staging into unpadded [128][32] ------
template <bool OUT_BF16>
__global__ __launch_bounds__(256) void k_gemm(
    const u16* __restrict__ A, const u16* __restrict__ Bt,
    void* __restrict__ out, const float* __restrict__ obias, const int N) {
  __shared__ u16 As[128 * 32];
  __shared__ u16 Bs[128 * 32];
  const int tid = threadIdx.x, wid = tid >> 6, lane = tid & 63;
  const int quad = lane >> 4, l16 = lane & 15;
  const int wm = (wid >> 1) * 64, wn = (wid & 1) * 64;
  const int bm = blockIdx.x, bn = blockIdx.y;
  const int r0 = wid * 16 + (lane >> 2);
  const int kc = (lane & 3) * 8;
  const u16* gA0 = A + (size_t)(bm * 128 + r0) * 256 + kc;
  const u16* gA1 = A + (size_t)(bm * 128 + 64 + r0) * 256 + kc;
  const u16* gB0 = Bt + (size_t)(bn * 128 + r0) * 256 + kc;
  const u16* gB1 = Bt + (size_t)(bn * 128 + 64 + r0) * 256 + kc;
  u16* lA0 = As + wid * 512;
  u16* lA1 = As + 2048 + wid * 512;
  u16* lB0 = Bs + wid * 512;
  u16* lB1 = Bs + 2048 + wid * 512;
  f32x4 acc[4][4];
#pragma unroll
  for (int i = 0; i < 4; i++)
#pragma unroll
    for (int j = 0; j < 4; j++) acc[i][j] = f32x4{0.f, 0.f, 0.f, 0.f};
  for (int k0 = 0; k0 < 256; k0 += 32) {
    __syncthreads();
    load_lds16(gA0 + k0, lA0);
    load_lds16(gA1 + k0, lA1);
    load_lds16(gB0 + k0, lB0);
    load_lds16(gB1 + k0, lB1);
    __syncthreads();
    short8 af[4], bf[4];
#pragma unroll
    for (int i = 0; i < 4; i++)
      af[i] = *(const short8*)(As + (wm + i * 16 + l16) * 32 + quad * 8);
#pragma unroll
    for (int j = 0; j < 4; j++)
      bf[j] = *(const short8*)(Bs + (wn + j * 16 + l16) * 32 + quad * 8);
#pragma unroll
    for (int i = 0; i < 4; i++)
#pragma unroll
      for (int j = 0; j < 4; j++)
        acc[i][j] = __builtin_amdgcn_mfma_f32_16x16x32_bf16(af[i], bf[j], acc[i][j], 0, 0, 0);
  }
#pragma unroll
  for (int i = 0; i < 4; i++)
#pragma unroll
    for (int j = 0; j < 4; j++)
#pragma unroll
      for (int r = 0; r < 4; r++) {
        const int gm = bm * 128 + wm + i * 16 + quad * 4 + r;
        const int gn = bn * 128 + wn + j * 16 + l16;
        const float v = acc[i][j][r];
        if (OUT_BF16) ((u16*)out)[(size_t)gm * N + gn] = f2b(v);
        else ((float*)out)[(size_t)gm * N + gn] = v + obias[gn];
      }
}

// ---- K5: attention, block = (b, h, q-half): 512 thr = 8 waves x 16 q.
//      K staged once via global_load_lds; V^T staged conflict-free; single
//      __syncthreads; PV through per-wave LDS quarters; coalesced Z stores ----
__global__ __launch_bounds__(512, 4) void k_attn(
    const u16* __restrict__ Y, const float* __restrict__ biasB,
    const float* __restrict__ mask, const float* __restrict__ gb,
    u16* __restrict__ Z) {
  __shared__ u16 Ks[256 * 32];     // [k][c] 16384 B
  __shared__ u16 Vt[32 * 272];     // [c][slot] 17408 B
  __shared__ u16 Ps[8][16 * 72];   // per-wave P quarter [16 q][64 slots+pad] 18432 B
  const int b = blockIdx.x, h = blockIdx.y, qh = blockIdx.z;
  const int tid = threadIdx.x, w = tid >> 6, lane = tid & 63;
  const int quad = lane >> 4, l16 = lane & 15;
  const int q0 = qh * 128 + w * 16;
  const u16* Yb = Y + (size_t)b * 256 * 1024;
  // ---- stage K [k][32c of head h] via async 16B loads (2 per wave) ----
  {
    const int kr = w * 32 + (lane >> 2), kc = (lane & 3) * 8;
    load_lds16(Yb + (size_t)kr * 1024 + 256 + h * 32 + kc, Ks + (w * 32) * 32);
    load_lds16(Yb + (size_t)(kr + 16) * 1024 + 256 + h * 32 + kc, Ks + (w * 32 + 16) * 32);
  }
  // ---- stage V^T permuted: thread t -> slot t&255, c-chunk (t>>8)*16 ----
  {
    const int slot = tid & 255, c0 = (tid >> 8) * 16;
    const int kv = ((slot >> 6) << 6) + ((slot & 3) << 4) + ((slot >> 2) & 15);
    const u16* src = Yb + (size_t)kv * 1024 + 512 + h * 32 + c0;
    union { uint4 q[2]; u16 u[16]; } uu;
    uu.q[0] = *(const uint4*)(src);
    uu.q[1] = *(const uint4*)(src + 8);
#pragma unroll
    for (int j = 0; j < 16; j++) Vt[(c0 + j) * 272 + slot] = uu.u[j];
  }
  // ---- Q frag + mask (global, before barrier) ----
  const short8 aq = *(const short8*)(Yb + (size_t)(q0 + l16) * 1024 + h * 32 + quad * 8);
  float maskv[16];
#pragma unroll
  for (int ni = 0; ni < 16; ni++)
    maskv[ni] = 1e9f * (mask[b * 256 + ni * 16 + l16] - 1.f);
  __syncthreads();  // K + V staging complete
  // ---- S = Q K^T : 16 MFMAs per wave ----
  f32x4 S[16];
#pragma unroll
  for (int ni = 0; ni < 16; ni++) S[ni] = f32x4{0.f, 0.f, 0.f, 0.f};
#pragma unroll
  for (int ni = 0; ni < 16; ni++) {
    const short8 bk = *(const short8*)(Ks + (ni * 16 + l16) * 32 + quad * 8);
    S[ni] = __builtin_amdgcn_mfma_f32_16x16x32_bf16(aq, bk, S[ni], 0, 0, 0);
  }
  // ---- + permuted pair bias + mask, softmax over k ----
  float li[4];
#pragma unroll
  for (int r = 0; r < 4; r++) {
    const int qg = q0 + quad * 4 + r;
    const float* bb = biasB + (h << 16) + (qg << 8) + l16 * 4;
    const float4 b0 = *(const float4*)(bb);
    const float4 b1 = *(const float4*)(bb + 64);
    const float4 b2 = *(const float4*)(bb + 128);
    const float4 b3 = *(const float4*)(bb + 192);
    float sv[16];
    sv[0] = S[0][r] + b0.x + maskv[0];   sv[1] = S[1][r] + b0.y + maskv[1];
    sv[2] = S[2][r] + b0.z + maskv[2];   sv[3] = S[3][r] + b0.w + maskv[3];
    sv[4] = S[4][r] + b1.x + maskv[4];   sv[5] = S[5][r] + b1.y + maskv[5];
    sv[6] = S[6][r] + b1.z + maskv[6];   sv[7] = S[7][r] + b1.w + maskv[7];
    sv[8] = S[8][r] + b2.x + maskv[8];   sv[9] = S[9][r] + b2.y + maskv[9];
    sv[10] = S[10][r] + b2.z + maskv[10]; sv[11] = S[11][r] + b2.w + maskv[11];
    sv[12] = S[12][r] + b3.x + maskv[12]; sv[13] = S[13][r] + b3.y + maskv[13];
    sv[14] = S[14][r] + b3.z + maskv[14]; sv[15] = S[15][r] + b3.w + maskv[15];
    float mx = -1e30f;
#pragma unroll
    for (int ni = 0; ni < 16; ni++) mx = fmaxf(mx, sv[ni]);
#pragma unroll
    for (int d = 1; d < 16; d <<= 1) mx = fmaxf(mx, __shfl_xor(mx, d));
    float l = 0.f;
#pragma unroll
    for (int ni = 0; ni < 16; ni++) {
      const float p = __expf(sv[ni] - mx);
      S[ni][r] = p;
      l += p;
    }
#pragma unroll
    for (int d = 1; d < 16; d <<= 1) l += __shfl_xor(l, d);
    li[r] = 1.f / l;
  }
  // ---- P @ V in 4 k-quarters through per-wave LDS (wave-in-order DS) ----
  f32x4 O[2];
  O[0] = f32x4{0.f, 0.f, 0.f, 0.f};
  O[1] = f32x4{0.f, 0.f, 0.f, 0.f};
  u16* Pw = Ps[w];
#pragma unroll
  for (int Q = 0; Q < 4; Q++) {
#pragma unroll
    for (int r = 0; r < 4; r++) {
      uint2 wv;  // slots l16*4..+3 of row quad*4+r
      wv.x = pkb(S[Q * 4 + 0][r], S[Q * 4 + 1][r]);
      wv.y = pkb(S[Q * 4 + 2][r], S[Q * 4 + 3][r]);
      *(uint2*)(Pw + (quad * 4 + r) * 72 + l16 * 4) = wv;
    }
#pragma unroll
    for (int ks = 0; ks < 2; ks++) {
      const short8 ap = *(const short8*)(Pw + l16 * 72 + ks * 32 + quad * 8);
#pragma unroll
      for (int nj = 0; nj < 2; nj++) {
        const short8 bv = *(const short8*)(Vt + (nj * 16 + l16) * 272 + Q * 64 + ks * 32 + quad * 8);
        O[nj] = __builtin_amdgcn_mfma_f32_16x16x32_bf16(ap, bv, O[nj], 0, 0, 0);
      }
    }
  }
  // ---- epilogue: 1/l, gate sigmoid, stage in Pw, coalesced 16B stores ----
  const float* gbh = gb + h * 32;
#pragma unroll
  for (int nj = 0; nj < 2; nj++)
#pragma unroll
    for (int r = 0; r < 4; r++) {
      const int qg = q0 + quad * 4 + r;
      const int c = nj * 16 + l16;
      const float wa = O[nj][r] * li[r];
      const float gv = b2f(Yb[(size_t)qg * 1024 + 768 + h * 32 + c]) + gbh[c];
      const float gate = 1.f / (1.f + __expf(-gv));
      Pw[(quad * 4 + r) * 40 + c] = f2b(wa * gate);  // Zs reuse of Pw, stride 40
    }
  {
    const int qr = lane >> 2, cc = (lane & 3) * 8;
    const uint4 zv = *(const uint4*)(Pw + qr * 40 + cc);
    *(uint4*)(Z + ((size_t)(b * 256 + q0 + qr)) * 256 + h * 32 + cc) = zv;
  }
}

extern "C" void kernel_launch(void* const* d_in, const int* in_sizes, int n_in,
                              void* d_out, int out_size, void* d_ws, size_t ws_size,
                              hipStream_t stream) {
  const float* msa  = (const float*)d_in[0];
  const float* mask = (const float*)d_in[1];
  const float* pair = (const float*)d_in[2];
  const float* qns  = (const float*)d_in[3];
  const float* qnb  = (const float*)d_in[4];
  const float* pns  = (const float*)d_in[5];
  const float* pnb  = (const float*)d_in[6];
  const float* f2w  = (const float*)d_in[7];
  const float* qw   = (const float*)d_in[8];
  const float* kw   = (const float*)d_in[9];
  const float* vw   = (const float*)d_in[10];
  const float* gw   = (const float*)d_in[11];
  const float* gbp  = (const float*)d_in[12];
  const float* ow   = (const float*)d_in[13];
  const float* ob   = (const float*)d_in[14];
  float* out = (float*)d_out;
  char* ws = (char*)d_ws;
  u16*   xb    = (u16*)(ws);                  // 16777216 B
  u16*   Wt    = (u16*)(ws + 16777216);       //   524288 B
  u16*   OWt   = (u16*)(ws + 17301504);       //   131072 B
  float* biasB = (float*)(ws + 17432576);     //  2097152 B
  u16*   Y     = (u16*)(ws + 19529728);       // 67108864 B
  u16*   Z     = (u16*)(ws + 86638592);       // 16777216 B

  k_ln_msa<<<8192, 256, 0, stream>>>(msa, qns, qnb, xb);
  k_ln_pair<<<2048, 256, 0, stream>>>(pair, pns, pnb, f2w, biasB);
  k_conv<<<1280, 256, 0, stream>>>(qw, kw, vw, gw, ow, Wt, OWt);
  k_gemm<true><<<dim3(256, 8), 256, 0, stream>>>(xb, Wt, (void*)Y, nullptr, 1024);
  k_attn<<<dim3(128, 8, 2), 512, 0, stream>>>(Y, biasB, mask, gbp, Z);
  k_gemm<false><<<dim3(256, 2), 256, 0, stream>>>(Z, OWt, (void*)out, ob, 256);
}